// Round 1
// baseline (118.768 us; speedup 1.0000x reference)
//
#include <hip/hip_runtime.h>

// Problem: B=2, N=1024, F_in=128, F_out=64
// out[b,i,f] = (1 - deg[b,i]) * xw[b,i,f] + sum_j w[b,i,j]*xw[b,j,f] + bias[f]
//   xw = x @ weight
//   w[b,i,j] = adj[b,i,j] / max(L1(xw_i, xw_j), 1e-3)
//   deg[b,i] = sum_j w[b,i,j]

#define TI 32
#define TJ 32
#define JS 8            // j-range splits per (b, i-tile) for occupancy: 2*32*8 = 512 blocks
#define XSTR 68         // padded LDS row stride (floats) for x tiles: breaks 64-float bank stride
#define WSTR 33         // padded stride for w tile

// ---------------- Kernel 1: xw = x @ W ----------------
__global__ __launch_bounds__(256) void gemm_xw(const float* __restrict__ x,
                                               const float* __restrict__ w,
                                               float* __restrict__ xw) {
    int idx = blockIdx.x * 256 + threadIdx.x;   // 0..131071
    int r = idx >> 6;                           // global row (b*1024+n), uniform per wave
    int f = idx & 63;
    const float* xrow = x + (size_t)r * 128;
    float acc = 0.f;
#pragma unroll 8
    for (int k = 0; k < 128; ++k) {
        acc += xrow[k] * w[k * 64 + f];         // xrow[k] scalar-broadcast, w coalesced
    }
    xw[idx] = acc;
}

__device__ __forceinline__ void absdiff_acc(float4& d, const float4 a, const float4 b) {
    d.x += fabsf(a.x - b.x);
    d.y += fabsf(a.y - b.y);
    d.z += fabsf(a.z - b.z);
    d.w += fabsf(a.w - b.w);
}

// ---------------- Kernel 2: fused distances + weighted aggregation (partial over j-range) ----
__global__ __launch_bounds__(256) void fused_gtv(const float* __restrict__ xw,
                                                 const float* __restrict__ adj,
                                                 float* __restrict__ out_acc,
                                                 float* __restrict__ deg_acc) {
    __shared__ float xi[TI * XSTR];
    __shared__ float xj[TJ * XSTR];
    __shared__ float adjt[TI * TJ];
    __shared__ float wt[TI * WSTR];

    const int bx  = blockIdx.x;
    const int js  = bx & 7;            // j-split index 0..7
    const int it  = (bx >> 3) & 31;    // i-tile 0..31
    const int b   = bx >> 8;           // batch 0..1
    const int tid = threadIdx.x;
    const int i0  = it * TI;

    const float* xwb  = xw  + (size_t)b * 1024 * 64;
    const float* adjb = adj + (size_t)b * 1024 * 1024;

    // stage xi tile once: 32 rows x 64 floats = 512 float4, 2 per thread
#pragma unroll
    for (int e = tid; e < TI * 16; e += 256) {
        int row = e >> 4, c = e & 15;
        float4 v = *(const float4*)&xwb[(i0 + row) * 64 + c * 4];
        *(float4*)&xi[row * XSTR + c * 4] = v;
    }

    // phase-2 identity: thread owns (i_loc, fg) -> 8 features
    const int i_loc = tid >> 3;
    const int fg    = tid & 7;
    float4 acc0 = {0.f, 0.f, 0.f, 0.f};
    float4 acc1 = {0.f, 0.f, 0.f, 0.f};
    float  degp = 0.f;

    for (int jt = 0; jt < 4; ++jt) {
        const int j0 = js * 128 + jt * TJ;

        // stage xj tile: 512 float4
#pragma unroll
        for (int e = tid; e < TJ * 16; e += 256) {
            int row = e >> 4, c = e & 15;
            float4 v = *(const float4*)&xwb[(j0 + row) * 64 + c * 4];
            *(float4*)&xj[row * XSTR + c * 4] = v;
        }
        // stage adj tile: 32x32 = 256 float4, 1 per thread
        {
            int row = tid >> 3, c = tid & 7;
            float4 v = *(const float4*)&adjb[(size_t)(i0 + row) * 1024 + j0 + c * 4];
            *(float4*)&adjt[row * TJ + c * 4] = v;
        }
        __syncthreads();

        // ---- phase 1: pairwise L1 distances, 2x2 per thread ----
        {
            const int bi = (tid >> 4) * 2;   // 0..30
            const int bj = (tid & 15) * 2;   // 0..30
            float4 d00 = {0,0,0,0}, d01 = {0,0,0,0}, d10 = {0,0,0,0}, d11 = {0,0,0,0};
            const float* xr0 = &xi[bi * XSTR];
            const float* xr1 = &xi[(bi + 1) * XSTR];
            const float* xc0 = &xj[bj * XSTR];
            const float* xc1 = &xj[(bj + 1) * XSTR];
#pragma unroll
            for (int c = 0; c < 16; ++c) {
                float4 a0 = *(const float4*)&xr0[c * 4];
                float4 a1 = *(const float4*)&xr1[c * 4];
                float4 b0 = *(const float4*)&xc0[c * 4];
                float4 b1 = *(const float4*)&xc1[c * 4];
                absdiff_acc(d00, a0, b0);
                absdiff_acc(d01, a0, b1);
                absdiff_acc(d10, a1, b0);
                absdiff_acc(d11, a1, b1);
            }
            float s00 = (d00.x + d00.y) + (d00.z + d00.w);
            float s01 = (d01.x + d01.y) + (d01.z + d01.w);
            float s10 = (d10.x + d10.y) + (d10.z + d10.w);
            float s11 = (d11.x + d11.y) + (d11.z + d11.w);
            wt[bi * WSTR + bj]           = adjt[bi * TJ + bj]           / fmaxf(s00, 1e-3f);
            wt[bi * WSTR + bj + 1]       = adjt[bi * TJ + bj + 1]       / fmaxf(s01, 1e-3f);
            wt[(bi + 1) * WSTR + bj]     = adjt[(bi + 1) * TJ + bj]     / fmaxf(s10, 1e-3f);
            wt[(bi + 1) * WSTR + bj + 1] = adjt[(bi + 1) * TJ + bj + 1] / fmaxf(s11, 1e-3f);
        }
        __syncthreads();

        // ---- phase 2: acc[f] += w * xj[f], deg += w ----
        {
            const float* wrow = &wt[i_loc * WSTR];
#pragma unroll 8
            for (int j = 0; j < TJ; ++j) {
                float wv = wrow[j];
                float4 v0 = *(const float4*)&xj[j * XSTR + fg * 8];
                float4 v1 = *(const float4*)&xj[j * XSTR + fg * 8 + 4];
                acc0.x += wv * v0.x; acc0.y += wv * v0.y;
                acc0.z += wv * v0.z; acc0.w += wv * v0.w;
                acc1.x += wv * v1.x; acc1.y += wv * v1.y;
                acc1.z += wv * v1.z; acc1.w += wv * v1.w;
                degp += wv;
            }
        }
        __syncthreads();   // before next tile overwrites xj/adjt/wt
    }

    // epilogue: atomically accumulate partials (8 j-splits per row)
    float* op = out_acc + ((size_t)b * 1024 + i0 + i_loc) * 64 + fg * 8;
    atomicAdd(&op[0], acc0.x);
    atomicAdd(&op[1], acc0.y);
    atomicAdd(&op[2], acc0.z);
    atomicAdd(&op[3], acc0.w);
    atomicAdd(&op[4], acc1.x);
    atomicAdd(&op[5], acc1.y);
    atomicAdd(&op[6], acc1.z);
    atomicAdd(&op[7], acc1.w);
    if (fg == 0) atomicAdd(&deg_acc[b * 1024 + i0 + i_loc], degp);
}

// ---------------- Kernel 3: out += (1-deg)*xw + bias ----------------
__global__ __launch_bounds__(256) void finish_gtv(const float* __restrict__ xw,
                                                  const float* __restrict__ deg,
                                                  const float* __restrict__ bias,
                                                  float* __restrict__ out) {
    int idx = blockIdx.x * 256 + threadIdx.x;   // 0..131071
    int r = idx >> 6;
    int f = idx & 63;
    out[idx] = out[idx] + (1.f - deg[r]) * xw[idx] + bias[f];
}

extern "C" void kernel_launch(void* const* d_in, const int* in_sizes, int n_in,
                              void* d_out, int out_size, void* d_ws, size_t ws_size,
                              hipStream_t stream) {
    const float* x    = (const float*)d_in[0];   // [2,1024,128]
    const float* adj  = (const float*)d_in[1];   // [2,1024,1024]
    const float* w    = (const float*)d_in[2];   // [128,64]
    const float* bias = (const float*)d_in[3];   // [64]
    float* out = (float*)d_out;                  // [2,1024,64]

    float* xw  = (float*)d_ws;                           // 2*1024*64 floats = 512 KB
    float* deg = (float*)((char*)d_ws + 2 * 1024 * 64 * sizeof(float)); // 2048 floats

    hipMemsetAsync(out, 0, 2 * 1024 * 64 * sizeof(float), stream);
    hipMemsetAsync(deg, 0, 2 * 1024 * sizeof(float), stream);

    gemm_xw<<<512, 256, 0, stream>>>(x, w, xw);
    fused_gtv<<<512, 256, 0, stream>>>(xw, adj, out, deg);
    finish_gtv<<<512, 256, 0, stream>>>(xw, deg, bias, out);
}

// Round 2
// 91.202 us; speedup vs baseline: 1.3023x; 1.3023x over previous
//
#include <hip/hip_runtime.h>

// Problem: B=2, N=1024, F_in=128, F_out=64
// out[b,i,f] = (1 - deg[b,i]) * xw[b,i,f] + sum_j w[b,i,j]*xw[b,j,f] + bias[f]
//   xw = x @ weight
//   w[b,i,j] = adj[b,i,j] / max(L1(xw_i, xw_j), 1e-3)
//   deg[b,i] = sum_j w[b,i,j]
//
// Structure: 64x64 (i,j) tiles, 16 j-splits -> grid 2*16*16 = 512 blocks.
// Each block: stage xi/xj swizzled in LDS -> phase1 4x4-blocked L1 distances
// -> w tile transposed in LDS -> phase2 weighted aggregation -> plain stores
// to a per-js partial buffer (no atomics). finish reduces partials.

#define JS 16

__device__ __forceinline__ void fma4(float4& a, float s, const float4 v) {
    a.x += s * v.x; a.y += s * v.y; a.z += s * v.z; a.w += s * v.w;
}

// ---------------- Kernel 1: xw = x @ W (LDS-staged) ----------------
__global__ __launch_bounds__(256) void gemm_xw(const float* __restrict__ x,
                                               const float* __restrict__ w,
                                               float* __restrict__ xw) {
    __shared__ float ws_[128 * 64];    // 32 KB, linear
    __shared__ float xs[16 * 132];     // pad 132: breaks rl*128 bank aliasing
    const int tid = threadIdx.x;
    const int r0  = blockIdx.x * 16;   // 128 blocks x 16 rows

#pragma unroll
    for (int e = tid; e < 2048; e += 256)  // 8192 floats of w
        ((float4*)ws_)[e] = ((const float4*)w)[e];
#pragma unroll
    for (int e = tid; e < 512; e += 256) { // 16 rows x 128 of x
        int row = e >> 5, c = e & 31;
        float4 v = *(const float4*)&x[(size_t)(r0 + row) * 128 + c * 4];
        *(float4*)&xs[row * 132 + c * 4] = v;
    }
    __syncthreads();

    const int rl = tid >> 4;   // 0..15 row
    const int fg = tid & 15;   // 4 features
    float4 acc = {0.f, 0.f, 0.f, 0.f};
#pragma unroll 8
    for (int k = 0; k < 128; ++k) {
        float xv = xs[rl * 132 + k];
        float4 wv = *(const float4*)&ws_[k * 64 + 4 * fg];
        fma4(acc, xv, wv);
    }
    *(float4*)&xw[(size_t)(r0 + rl) * 64 + 4 * fg] = acc;
}

// ---------------- Kernel 2: fused distances + aggregation ----------------
// ATOMIC=false: store partials to pout[js*2+b] slots. ATOMIC=true: atomicAdd
// into out/deg (fallback when ws too small; requires pre-zeroed buffers).
template <bool ATOMIC>
__global__ __launch_bounds__(256) void fused_gtv(const float* __restrict__ xw,
                                                 const float* __restrict__ adj,
                                                 float* __restrict__ pout,
                                                 float* __restrict__ pdeg) {
    __shared__ float xi[64 * 64];   // swizzled: block c of row r at c^((r>>2)&7)
    __shared__ float xj[64 * 64];
    __shared__ float wt[64 * 68];   // transposed: wt[j][i], stride 68

    const int tid = threadIdx.x;
    const int bx  = blockIdx.x;
    const int js  = bx & 15;
    const int it  = (bx >> 4) & 15;
    const int b   = bx >> 8;
    const int i0  = it * 64;
    const int j0  = js * 64;

    const float* xwb  = xw  + (size_t)b * 65536;
    const float* adjb = adj + (size_t)b * 1048576;

    const int ty = tid >> 4;   // 0..15 -> i rows 4ty..4ty+3
    const int tx = tid & 15;   // 0..15 -> j cols 4tx..4tx+3

    // prefetch adj 4x4 block (rows coalesce 256B across tx)
    float4 av[4];
#pragma unroll
    for (int r = 0; r < 4; ++r)
        av[r] = *(const float4*)&adjb[(size_t)(i0 + 4 * ty + r) * 1024 + j0 + 4 * tx];

    // stage xi, xj swizzled: 1024 float4 each, 4 per thread
#pragma unroll
    for (int e = tid; e < 1024; e += 256) {
        int row = e >> 4, c = e & 15;
        int sc  = (c ^ ((row >> 2) & 7)) << 2;
        float4 vi = *(const float4*)&xwb[(i0 + row) * 64 + c * 4];
        float4 vj = *(const float4*)&xwb[(j0 + row) * 64 + c * 4];
        *(float4*)&xi[row * 64 + sc] = vi;
        *(float4*)&xj[row * 64 + sc] = vj;
    }
    __syncthreads();

    // ---- phase 1: 4x4 pairwise L1 distances ----
    float d[4][4];
#pragma unroll
    for (int r = 0; r < 4; ++r)
#pragma unroll
        for (int q = 0; q < 4; ++q) d[r][q] = 0.f;

    const int sy = ty & 7, sx = tx & 7;
#pragma unroll
    for (int c = 0; c < 16; ++c) {
        float4 a[4], bb[4];
#pragma unroll
        for (int r = 0; r < 4; ++r)
            a[r] = *(const float4*)&xi[(4 * ty + r) * 64 + ((c ^ sy) << 2)];
#pragma unroll
        for (int q = 0; q < 4; ++q)
            bb[q] = *(const float4*)&xj[(4 * tx + q) * 64 + ((c ^ sx) << 2)];
#pragma unroll
        for (int r = 0; r < 4; ++r)
#pragma unroll
            for (int q = 0; q < 4; ++q) {
                float t0 = a[r].x - bb[q].x;
                float t1 = a[r].y - bb[q].y;
                float t2 = a[r].z - bb[q].z;
                float t3 = a[r].w - bb[q].w;
                d[r][q] += (fabsf(t0) + fabsf(t1)) + (fabsf(t2) + fabsf(t3));
            }
    }

    // w = adj / max(d, 1e-3), store transposed wt[j][i]
    {
        const float* ac[4] = {&av[0].x, &av[1].x, &av[2].x, &av[3].x};
#pragma unroll
        for (int r = 0; r < 4; ++r)
#pragma unroll
            for (int q = 0; q < 4; ++q)
                wt[(4 * tx + q) * 68 + 4 * ty + r] = ac[r][q] / fmaxf(d[r][q], 1e-3f);
    }
    __syncthreads();

    // ---- phase 2: acc[i][f] += w[i][j] * xj[j][f] ----
    const int i4 = tid >> 4;   // rows 4*i4..+3
    const int fg = tid & 15;   // features 4*fg..+3
    float4 acc[4] = {{0,0,0,0},{0,0,0,0},{0,0,0,0},{0,0,0,0}};
    float  dg[4]  = {0.f, 0.f, 0.f, 0.f};
#pragma unroll 4
    for (int j = 0; j < 64; ++j) {
        float4 wv = *(const float4*)&wt[j * 68 + 4 * i4];
        float4 xv = *(const float4*)&xj[j * 64 + ((fg ^ ((j >> 2) & 7)) << 2)];
        fma4(acc[0], wv.x, xv);
        fma4(acc[1], wv.y, xv);
        fma4(acc[2], wv.z, xv);
        fma4(acc[3], wv.w, xv);
        dg[0] += wv.x; dg[1] += wv.y; dg[2] += wv.z; dg[3] += wv.w;
    }

    if (ATOMIC) {
#pragma unroll
        for (int r = 0; r < 4; ++r) {
            float* op = pout + ((size_t)b * 1024 + i0 + 4 * i4 + r) * 64 + 4 * fg;
            atomicAdd(&op[0], acc[r].x);
            atomicAdd(&op[1], acc[r].y);
            atomicAdd(&op[2], acc[r].z);
            atomicAdd(&op[3], acc[r].w);
            if (fg == 0) atomicAdd(&pdeg[b * 1024 + i0 + 4 * i4 + r], dg[r]);
        }
    } else {
        const size_t slot = (size_t)(js * 2 + b) * 65536;
#pragma unroll
        for (int r = 0; r < 4; ++r) {
            *(float4*)&pout[slot + (i0 + 4 * i4 + r) * 64 + 4 * fg] = acc[r];
            if (fg == 0) pdeg[(js * 2 + b) * 1024 + i0 + 4 * i4 + r] = dg[r];
        }
    }
}

// ---------------- Kernel 3: reduce partials + identity + bias ----------------
template <bool ATOMIC>
__global__ __launch_bounds__(256) void finish_gtv(const float* __restrict__ xw,
                                                  const float* __restrict__ part,
                                                  const float* __restrict__ pdeg,
                                                  const float* __restrict__ bias,
                                                  float* __restrict__ out) {
    int idx = blockIdx.x * 256 + threadIdx.x;  // 0..131071
    int f = idx & 63;
    int r = idx >> 6;           // b*1024 + n
    int b = r >> 10;
    if (ATOMIC) {
        out[idx] = out[idx] + (1.f - pdeg[r]) * xw[idx] + bias[f];
    } else {
        int loc = idx & 65535;  // n*64+f within batch
        int n   = r & 1023;
        float s = 0.f, dgs = 0.f;
#pragma unroll
        for (int js = 0; js < JS; ++js) {
            s   += part[(size_t)(js * 2 + b) * 65536 + loc];
            dgs += pdeg[(js * 2 + b) * 1024 + n];
        }
        out[idx] = s + (1.f - dgs) * xw[idx] + bias[f];
    }
}

extern "C" void kernel_launch(void* const* d_in, const int* in_sizes, int n_in,
                              void* d_out, int out_size, void* d_ws, size_t ws_size,
                              hipStream_t stream) {
    const float* x    = (const float*)d_in[0];   // [2,1024,128]
    const float* adj  = (const float*)d_in[1];   // [2,1024,1024]
    const float* w    = (const float*)d_in[2];   // [128,64]
    const float* bias = (const float*)d_in[3];   // [64]
    float* out = (float*)d_out;                  // [2,1024,64]

    float* xw   = (float*)d_ws;                               // 512 KB
    float* pdeg = (float*)((char*)d_ws + 512 * 1024);         // 32*1024*4 = 128 KB
    float* part = (float*)((char*)d_ws + 512 * 1024 + 128 * 1024);  // 8 MB
    const size_t NEED = 512 * 1024 + 128 * 1024 + (size_t)32 * 65536 * 4;

    gemm_xw<<<128, 256, 0, stream>>>(x, w, xw);

    if (ws_size >= NEED) {
        fused_gtv<false><<<512, 256, 0, stream>>>(xw, adj, part, pdeg);
        finish_gtv<false><<<512, 256, 0, stream>>>(xw, part, pdeg, bias, out);
    } else {
        // fallback: atomic accumulation directly into out (round-1 scheme)
        hipMemsetAsync(out, 0, 2 * 1024 * 64 * sizeof(float), stream);
        hipMemsetAsync(pdeg, 0, 2 * 1024 * sizeof(float), stream);
        fused_gtv<true><<<512, 256, 0, stream>>>(xw, adj, out, pdeg);
        finish_gtv<true><<<512, 256, 0, stream>>>(xw, nullptr, pdeg, bias, out);
    }
}

// Round 3
// 88.269 us; speedup vs baseline: 1.3455x; 1.0332x over previous
//
#include <hip/hip_runtime.h>
#include <hip/hip_fp16.h>

// Problem: B=2, N=1024, F_in=128, F_out=64
// out[b,i,f] = (1 - deg[b,i]) * xw[b,i,f] + sum_j w[b,i,j]*xw[b,j,f] + bias[f]
//   w[b,i,j] = adj[b,i,j] / max(L1(xw_i, xw_j), 1e-3), deg = row-sum of w
//
// R3: 32x64 (i,j) tiles -> grid 1024 (4 blocks/CU). Phase-1 distances in
// packed __half2 (2x VALU rate, half LDS traffic); phase-2 aggregation fp32.
// Partials to ws (no atomics), reduced by finish.

#define JS 16
#define HSTR 72   // __half row stride: 144 B (16B-aligned blocks, ~2-way worst banking)

__device__ __forceinline__ void fma4(float4& a, float s, const float4 v) {
    a.x += s * v.x; a.y += s * v.y; a.z += s * v.z; a.w += s * v.w;
}

// ---------------- Kernel 1: xw = x @ W, also emit f16 copy ----------------
__global__ __launch_bounds__(256) void gemm_xw(const float* __restrict__ x,
                                               const float* __restrict__ w,
                                               float* __restrict__ xw,
                                               __half* __restrict__ xwh) {
    __shared__ float ws_[128 * 64];   // 32 KB
    __shared__ float xs[8 * 132];
    const int tid = threadIdx.x;
    const int r0  = blockIdx.x * 8;   // 256 blocks x 8 rows

#pragma unroll
    for (int e = tid; e < 2048; e += 256)
        ((float4*)ws_)[e] = ((const float4*)w)[e];
    {
        int row = tid >> 5, c = tid & 31;   // 8 rows x 32 float4
        float4 v = *(const float4*)&x[(size_t)(r0 + row) * 128 + c * 4];
        *(float4*)&xs[row * 132 + c * 4] = v;
    }
    __syncthreads();

    const int rl = tid >> 5;   // 0..7
    const int fg = tid & 31;   // 2 features
    float2 acc = {0.f, 0.f};
#pragma unroll 8
    for (int k = 0; k < 128; ++k) {
        float xv = xs[rl * 132 + k];
        float2 wv = *(const float2*)&ws_[k * 64 + 2 * fg];
        acc.x += xv * wv.x; acc.y += xv * wv.y;
    }
    size_t o = (size_t)(r0 + rl) * 64 + 2 * fg;
    *(float2*)&xw[o] = acc;
    *(__half2*)&xwh[o] = __floats2half2_rn(acc.x, acc.y);
}

// ---------------- Kernel 2: fused distances + aggregation ----------------
template <bool ATOMIC>
__global__ __launch_bounds__(256) void fused_gtv(const float* __restrict__ xw,
                                                 const __half* __restrict__ xwh,
                                                 const float* __restrict__ adj,
                                                 float* __restrict__ pout,
                                                 float* __restrict__ pdeg) {
    __shared__ __half xih[32 * HSTR];   // 4.5 KB
    __shared__ __half xjh[64 * HSTR];   // 9 KB
    __shared__ float  xjf[64 * 64];     // 16 KB
    __shared__ float  wt[64 * 36];      // 9 KB, transposed wt[j][i]

    const int tid = threadIdx.x;
    const int bx  = blockIdx.x;
    const int js  = bx & 15;
    const int it  = (bx >> 4) & 31;
    const int b   = bx >> 9;
    const int i0  = it * 32;
    const int j0  = js * 64;

    const float*  xwb = xw  + (size_t)b * 65536;
    const __half* xhb = xwh + (size_t)b * 65536;
    const float*  adjb = adj + (size_t)b * 1048576;

    const int ty = tid >> 5;   // 0..7  -> i rows 4ty..4ty+3
    const int tx = tid & 31;   // 0..31 -> j cols 2tx..2tx+1

    // prefetch adj 4x2 block (256B coalesced per row across tx)
    float2 av[4];
#pragma unroll
    for (int r = 0; r < 4; ++r)
        av[r] = *(const float2*)&adjb[(size_t)(i0 + 4 * ty + r) * 1024 + j0 + 2 * tx];

    // stage xih: 32 rows x 8 16B-blocks = 256
    {
        int row = tid >> 3, c = tid & 7;
        float4 v = *(const float4*)&xhb[(i0 + row) * 64 + c * 8];
        *(float4*)&xih[row * HSTR + c * 8] = v;
    }
    // stage xjh: 64 rows x 8 blocks = 512
#pragma unroll
    for (int e = tid; e < 512; e += 256) {
        int row = e >> 3, c = e & 7;
        float4 v = *(const float4*)&xhb[(j0 + row) * 64 + c * 8];
        *(float4*)&xjh[row * HSTR + c * 8] = v;
    }
    // stage xjf: 64 rows x 16 float4 = 1024
#pragma unroll
    for (int e = tid; e < 1024; e += 256) {
        int row = e >> 4, c = e & 15;
        float4 v = *(const float4*)&xwb[(j0 + row) * 64 + c * 4];
        *(float4*)&xjf[row * 64 + c * 4] = v;
    }
    __syncthreads();

    // ---- phase 1: 4x2 pairwise L1 distances in packed f16 ----
    __half2 acc[4][2];
#pragma unroll
    for (int r = 0; r < 4; ++r)
#pragma unroll
        for (int q = 0; q < 2; ++q) acc[r][q] = __floats2half2_rn(0.f, 0.f);

#pragma unroll
    for (int c = 0; c < 8; ++c) {       // 8 features (4 half2) per step
        float4 a[4], bb[2];
#pragma unroll
        for (int r = 0; r < 4; ++r)
            a[r] = *(const float4*)&xih[(4 * ty + r) * HSTR + c * 8];
#pragma unroll
        for (int q = 0; q < 2; ++q)
            bb[q] = *(const float4*)&xjh[(2 * tx + q) * HSTR + c * 8];
#pragma unroll
        for (int r = 0; r < 4; ++r) {
            const __half2* pa = (const __half2*)&a[r];
#pragma unroll
            for (int q = 0; q < 2; ++q) {
                const __half2* pb = (const __half2*)&bb[q];
#pragma unroll
                for (int m = 0; m < 4; ++m)
                    acc[r][q] = __hadd2(acc[r][q], __habs2(__hsub2(pa[m], pb[m])));
            }
        }
    }

    // w = adj / max(d,1e-3), store transposed wt[j][i] as float4 over i
#pragma unroll
    for (int q = 0; q < 2; ++q) {
        float4 wq;
        float* wp = &wq.x;
#pragma unroll
        for (int r = 0; r < 4; ++r) {
            float d = __low2float(acc[r][q]) + __high2float(acc[r][q]);
            wp[r] = (&av[r].x)[q] / fmaxf(d, 1e-3f);
        }
        *(float4*)&wt[(2 * tx + q) * 36 + 4 * ty] = wq;
    }
    __syncthreads();

    // ---- phase 2: acc2[i][f] += w[i][j] * xjf[j][f] ----
    const int i2 = tid >> 4;   // rows 2*i2, 2*i2+1
    const int fg = tid & 15;   // features 4*fg..+3
    float4 acc2[2] = {{0,0,0,0},{0,0,0,0}};
    float  dg[2]   = {0.f, 0.f};
#pragma unroll 8
    for (int j = 0; j < 64; ++j) {
        float2 wv = *(const float2*)&wt[j * 36 + 2 * i2];
        float4 xv = *(const float4*)&xjf[j * 64 + 4 * fg];
        fma4(acc2[0], wv.x, xv);
        fma4(acc2[1], wv.y, xv);
        dg[0] += wv.x; dg[1] += wv.y;
    }

    if (ATOMIC) {
#pragma unroll
        for (int r = 0; r < 2; ++r) {
            float* op = pout + ((size_t)b * 1024 + i0 + 2 * i2 + r) * 64 + 4 * fg;
            float* ap = &acc2[r].x;
#pragma unroll
            for (int m = 0; m < 4; ++m) atomicAdd(&op[m], ap[m]);
            if (fg == 0) atomicAdd(&pdeg[b * 1024 + i0 + 2 * i2 + r], dg[r]);
        }
    } else {
        const size_t slot = (size_t)(js * 2 + b) * 65536;
#pragma unroll
        for (int r = 0; r < 2; ++r) {
            *(float4*)&pout[slot + (i0 + 2 * i2 + r) * 64 + 4 * fg] = acc2[r];
            if (fg == 0) pdeg[(js * 2 + b) * 1024 + i0 + 2 * i2 + r] = dg[r];
        }
    }
}

// ---------------- Kernel 3: reduce partials + identity + bias ----------------
template <bool ATOMIC>
__global__ __launch_bounds__(256) void finish_gtv(const float* __restrict__ xw,
                                                  const float* __restrict__ part,
                                                  const float* __restrict__ pdeg,
                                                  const float* __restrict__ bias,
                                                  float* __restrict__ out) {
    int idx = blockIdx.x * 256 + threadIdx.x;  // 0..131071
    int f = idx & 63;
    int r = idx >> 6;           // b*1024 + n
    int b = r >> 10;
    if (ATOMIC) {
        out[idx] = out[idx] + (1.f - pdeg[r]) * xw[idx] + bias[f];
    } else {
        int loc = idx & 65535;
        int n   = r & 1023;
        float s = 0.f, dgs = 0.f;
#pragma unroll
        for (int js = 0; js < JS; ++js) {
            s   += part[(size_t)(js * 2 + b) * 65536 + loc];
            dgs += pdeg[(js * 2 + b) * 1024 + n];
        }
        out[idx] = s + (1.f - dgs) * xw[idx] + bias[f];
    }
}

extern "C" void kernel_launch(void* const* d_in, const int* in_sizes, int n_in,
                              void* d_out, int out_size, void* d_ws, size_t ws_size,
                              hipStream_t stream) {
    const float* x    = (const float*)d_in[0];   // [2,1024,128]
    const float* adj  = (const float*)d_in[1];   // [2,1024,1024]
    const float* w    = (const float*)d_in[2];   // [128,64]
    const float* bias = (const float*)d_in[3];   // [64]
    float* out = (float*)d_out;                  // [2,1024,64]

    char* wsb = (char*)d_ws;
    float*  xw   = (float*)wsb;                     // 512 KB
    __half* xwh  = (__half*)(wsb + 512 * 1024);     // 256 KB
    float*  pdeg = (float*)(wsb + 768 * 1024);      // 128 KB (32 slots x 1024)
    float*  part = (float*)(wsb + 896 * 1024);      // 8 MB (32 slots x 65536)
    const size_t NEED = 896 * 1024 + (size_t)32 * 65536 * 4;

    gemm_xw<<<256, 256, 0, stream>>>(x, w, xw, xwh);

    if (ws_size >= NEED) {
        fused_gtv<false><<<1024, 256, 0, stream>>>(xw, xwh, adj, part, pdeg);
        finish_gtv<false><<<512, 256, 0, stream>>>(xw, part, pdeg, bias, out);
    } else {
        hipMemsetAsync(out, 0, 2 * 1024 * 64 * sizeof(float), stream);
        hipMemsetAsync(pdeg, 0, 2 * 1024 * sizeof(float), stream);
        fused_gtv<true><<<1024, 256, 0, stream>>>(xw, xwh, adj, out, pdeg);
        finish_gtv<true><<<512, 256, 0, stream>>>(xw, nullptr, pdeg, bias, out);
    }
}

// Round 4
// 85.080 us; speedup vs baseline: 1.3960x; 1.0375x over previous
//
#include <hip/hip_runtime.h>
#include <hip/hip_fp16.h>

// Problem: B=2, N=1024, F_in=128, F_out=64
// out[b,i,f] = (1 - deg[b,i]) * xw[b,i,f] + sum_j w[b,i,j]*xw[b,j,f] + bias[f]
//   w[b,i,j] = adj[b,i,j] / max(L1(xw_i, xw_j), 1e-3), deg = row-sum of w
// Diagonal w_ii cancels identically in the output -> excluded from both w and
// deg (keeps |w| <= ~0.03, safe for f16 MFMA aggregation).
//
// R4: 32x64 (i,j) tiles, grid 1024 (4 blocks/CU). Phase 1: packed-f16 L1
// distances (4x2 register blocking) + shfl deg reduction. Phase 2: f16 MFMA
// (16x16x32) for the weighted aggregation, fp32 accumulate. Partials to ws.

#define JS 16
#define HSTR 72   // __half row stride (144 B: 16B-aligned, 2-way banking = free)

typedef _Float16 half8_t __attribute__((ext_vector_type(8)));
typedef float    f32x4_t __attribute__((ext_vector_type(4)));

// ---------------- Kernel 1: xw = x @ W; emit f32, f16, and f16-transposed ----
__global__ __launch_bounds__(256) void gemm_xw(const float* __restrict__ x,
                                               const float* __restrict__ w,
                                               float* __restrict__ xw,
                                               __half* __restrict__ xwh,
                                               __half* __restrict__ xwt) {
    __shared__ float ws_[128 * 64];   // 32 KB
    __shared__ float xs[8 * 132];
    __shared__ __half ts[8 * 64];     // transpose staging
    const int tid = threadIdx.x;
    const int r0  = blockIdx.x * 8;   // 256 blocks x 8 rows

#pragma unroll
    for (int e = tid; e < 2048; e += 256)
        ((float4*)ws_)[e] = ((const float4*)w)[e];
    {
        int row = tid >> 5, c = tid & 31;
        float4 v = *(const float4*)&x[(size_t)(r0 + row) * 128 + c * 4];
        *(float4*)&xs[row * 132 + c * 4] = v;
    }
    __syncthreads();

    const int rl = tid >> 5;   // 0..7
    const int fg = tid & 31;   // 2 features
    float2 acc = {0.f, 0.f};
#pragma unroll 8
    for (int k = 0; k < 128; ++k) {
        float xv = xs[rl * 132 + k];
        float2 wv = *(const float2*)&ws_[k * 64 + 2 * fg];
        acc.x += xv * wv.x; acc.y += xv * wv.y;
    }
    size_t o = (size_t)(r0 + rl) * 64 + 2 * fg;
    *(float2*)&xw[o] = acc;
    __half2 h2 = __floats2half2_rn(acc.x, acc.y);
    *(__half2*)&xwh[o] = h2;
    *(__half2*)&ts[rl * 64 + 2 * fg] = h2;
    __syncthreads();

    // transpose epilogue: xwt[b][f][n0..n0+7] <- ts[0..7][f]
    if (tid < 64) {
        const int f = tid;
        const int b = r0 >> 10;
        const int n0 = r0 & 1023;
        __half hv[8];
#pragma unroll
        for (int r = 0; r < 8; ++r) hv[r] = ts[r * 64 + f];
        *(half8_t*)&xwt[((size_t)(b * 64 + f)) * 1024 + n0] = *(half8_t*)hv;
    }
}

// ---------------- Kernel 2: fused distances + MFMA aggregation ----------------
template <bool ATOMIC>
__global__ __launch_bounds__(256) void fused_gtv(const __half* __restrict__ xwh,
                                                 const __half* __restrict__ xwt,
                                                 const float* __restrict__ adj,
                                                 float* __restrict__ pout,
                                                 float* __restrict__ pdeg) {
    __shared__ __half xih[32 * HSTR];   // 4.5 KB  [i][f]
    __shared__ __half xjh[64 * HSTR];   // 9 KB    [j][f]
    __shared__ __half xjt[64 * HSTR];   // 9 KB    [f][j]  (MFMA B operand)
    __shared__ __half wt[32 * HSTR];    // 4.5 KB  [i][j]  (MFMA A operand)

    const int tid = threadIdx.x;
    const int bx  = blockIdx.x;
    const int js  = bx & 15;
    const int it  = (bx >> 4) & 31;
    const int b   = bx >> 9;
    const int i0  = it * 32;
    const int j0  = js * 64;

    const __half* xhb = xwh + (size_t)b * 65536;
    const __half* xtb = xwt + (size_t)b * 65536;
    const float*  adjb = adj + (size_t)b * 1048576;

    const int ty = tid >> 5;   // 0..7  -> i rows 4ty..4ty+3
    const int tx = tid & 31;   // 0..31 -> j cols 2tx..2tx+1

    // prefetch adj 4x2 block
    float2 av[4];
#pragma unroll
    for (int r = 0; r < 4; ++r)
        av[r] = *(const float2*)&adjb[(size_t)(i0 + 4 * ty + r) * 1024 + j0 + 2 * tx];

    // stage xih (256 x 16B), xjh (512 x 16B), xjt (512 x 16B)
    {
        int row = tid >> 3, c = tid & 7;
        float4 v = *(const float4*)&xhb[(i0 + row) * 64 + c * 8];
        *(float4*)&xih[row * HSTR + c * 8] = v;
    }
#pragma unroll
    for (int e = tid; e < 512; e += 256) {
        int row = e >> 3, c = e & 7;
        float4 v = *(const float4*)&xhb[(j0 + row) * 64 + c * 8];
        *(float4*)&xjh[row * HSTR + c * 8] = v;
        float4 t = *(const float4*)&xtb[row * 1024 + j0 + c * 8];  // row = f here
        *(float4*)&xjt[row * HSTR + c * 8] = t;
    }
    __syncthreads();

    // ---- phase 1: 4x2 pairwise L1 distances in packed f16 ----
    __half2 acc[4][2];
#pragma unroll
    for (int r = 0; r < 4; ++r)
#pragma unroll
        for (int q = 0; q < 2; ++q) acc[r][q] = __floats2half2_rn(0.f, 0.f);

#pragma unroll
    for (int c = 0; c < 8; ++c) {
        float4 a[4], bb[2];
#pragma unroll
        for (int r = 0; r < 4; ++r)
            a[r] = *(const float4*)&xih[(4 * ty + r) * HSTR + c * 8];
#pragma unroll
        for (int q = 0; q < 2; ++q)
            bb[q] = *(const float4*)&xjh[(2 * tx + q) * HSTR + c * 8];
#pragma unroll
        for (int r = 0; r < 4; ++r) {
            const __half2* pa = (const __half2*)&a[r];
#pragma unroll
            for (int q = 0; q < 2; ++q) {
                const __half2* pb = (const __half2*)&bb[q];
#pragma unroll
                for (int m = 0; m < 4; ++m)
                    acc[r][q] = __hadd2(acc[r][q], __habs2(__hsub2(pa[m], pb[m])));
            }
        }
    }

    // w = adj/max(d,1e-3), diagonal excluded; write f16 wt[i][j]; deg partials
    float dsum[4];
#pragma unroll
    for (int r = 0; r < 4; ++r) {
        const int gi = i0 + 4 * ty + r;
        float wv[2];
#pragma unroll
        for (int q = 0; q < 2; ++q) {
            const int gj = j0 + 2 * tx + q;
            float d = __low2float(acc[r][q]) + __high2float(acc[r][q]);
            float v = (&av[r].x)[q] / fmaxf(d, 1e-3f);
            wv[q] = (gi == gj) ? 0.f : v;
        }
        *(__half2*)&wt[(4 * ty + r) * HSTR + 2 * tx] = __floats2half2_rn(wv[0], wv[1]);
        dsum[r] = wv[0] + wv[1];
    }
    // deg reduction across tx (32 lanes within the wave)
#pragma unroll
    for (int r = 0; r < 4; ++r) {
#pragma unroll
        for (int m = 1; m < 32; m <<= 1)
            dsum[r] += __shfl_xor(dsum[r], m, 32);
    }
    if (tx == 0) {
#pragma unroll
        for (int r = 0; r < 4; ++r) {
            if (ATOMIC) atomicAdd(&pdeg[b * 1024 + i0 + 4 * ty + r], dsum[r]);
            else pdeg[(js * 2 + b) * 1024 + i0 + 4 * ty + r] = dsum[r];
        }
    }
    __syncthreads();

    // ---- phase 2: MFMA  P[32x64] = W[32x64(j)] x Xj[64(j)x64(f)] ----
    // wave wv: m16 = wv&1 (i-tile), n16 in {2*(wv>>1), 2*(wv>>1)+1} (f-tiles)
    const int wv   = tid >> 6;
    const int lane = tid & 63;
    const int quad = lane >> 4;
    const int l15  = lane & 15;
    const int m16  = wv & 1;
    const int npair = wv >> 1;

    f32x4_t c0 = {0.f, 0.f, 0.f, 0.f};
    f32x4_t c1 = {0.f, 0.f, 0.f, 0.f};
#pragma unroll
    for (int s = 0; s < 2; ++s) {
        half8_t af = *(half8_t*)&wt[(m16 * 16 + l15) * HSTR + s * 32 + quad * 8];
        half8_t b0 = *(half8_t*)&xjt[((npair * 2 + 0) * 16 + l15) * HSTR + s * 32 + quad * 8];
        half8_t b1 = *(half8_t*)&xjt[((npair * 2 + 1) * 16 + l15) * HSTR + s * 32 + quad * 8];
        c0 = __builtin_amdgcn_mfma_f32_16x16x32_f16(af, b0, c0, 0, 0, 0);
        c1 = __builtin_amdgcn_mfma_f32_16x16x32_f16(af, b1, c1, 0, 0, 0);
    }

    // epilogue: C row = m16*16 + quad*4 + r, col = n16*16 + l15
    if (ATOMIC) {
#pragma unroll
        for (int r = 0; r < 4; ++r) {
            int row = m16 * 16 + quad * 4 + r;
            atomicAdd(&pout[((size_t)b * 1024 + i0 + row) * 64 + (npair * 2) * 16 + l15], c0[r]);
            atomicAdd(&pout[((size_t)b * 1024 + i0 + row) * 64 + (npair * 2 + 1) * 16 + l15], c1[r]);
        }
    } else {
        const size_t slot = (size_t)(js * 2 + b) * 65536;
#pragma unroll
        for (int r = 0; r < 4; ++r) {
            int row = m16 * 16 + quad * 4 + r;
            pout[slot + (i0 + row) * 64 + (npair * 2) * 16 + l15] = c0[r];
            pout[slot + (i0 + row) * 64 + (npair * 2 + 1) * 16 + l15] = c1[r];
        }
    }
}

// ---------------- Kernel 3: reduce partials + identity + bias ----------------
template <bool ATOMIC>
__global__ __launch_bounds__(256) void finish_gtv(const float* __restrict__ xw,
                                                  const float* __restrict__ part,
                                                  const float* __restrict__ pdeg,
                                                  const float* __restrict__ bias,
                                                  float* __restrict__ out) {
    int idx = blockIdx.x * 256 + threadIdx.x;  // 0..131071
    int f = idx & 63;
    int r = idx >> 6;           // b*1024 + n
    int b = r >> 10;
    if (ATOMIC) {
        out[idx] = out[idx] + (1.f - pdeg[r]) * xw[idx] + bias[f];
    } else {
        int loc = idx & 65535;
        int n   = r & 1023;
        float s = 0.f, dgs = 0.f;
#pragma unroll
        for (int js = 0; js < JS; ++js) {
            s   += part[(size_t)(js * 2 + b) * 65536 + loc];
            dgs += pdeg[(js * 2 + b) * 1024 + n];
        }
        out[idx] = s + (1.f - dgs) * xw[idx] + bias[f];
    }
}

extern "C" void kernel_launch(void* const* d_in, const int* in_sizes, int n_in,
                              void* d_out, int out_size, void* d_ws, size_t ws_size,
                              hipStream_t stream) {
    const float* x    = (const float*)d_in[0];   // [2,1024,128]
    const float* adj  = (const float*)d_in[1];   // [2,1024,1024]
    const float* w    = (const float*)d_in[2];   // [128,64]
    const float* bias = (const float*)d_in[3];   // [64]
    float* out = (float*)d_out;                  // [2,1024,64]

    char* wsb = (char*)d_ws;
    float*  xw   = (float*)wsb;                      // 512 KB
    __half* xwh  = (__half*)(wsb + 512 * 1024);      // 256 KB  [b][n][f]
    __half* xwt  = (__half*)(wsb + 768 * 1024);      // 256 KB  [b][f][n]
    float*  pdeg = (float*)(wsb + 1024 * 1024);      // 128 KB (32 x 1024)
    float*  part = (float*)(wsb + 1152 * 1024);      // 8 MB  (32 x 65536)
    const size_t NEED = 1152 * 1024 + (size_t)32 * 65536 * 4;

    gemm_xw<<<256, 256, 0, stream>>>(x, w, xw, xwh, xwt);

    if (ws_size >= NEED) {
        fused_gtv<false><<<1024, 256, 0, stream>>>(xwh, xwt, adj, part, pdeg);
        finish_gtv<false><<<512, 256, 0, stream>>>(xw, part, pdeg, bias, out);
    } else {
        hipMemsetAsync(out, 0, 2 * 1024 * 64 * sizeof(float), stream);
        hipMemsetAsync(pdeg, 0, 2 * 1024 * sizeof(float), stream);
        fused_gtv<true><<<1024, 256, 0, stream>>>(xwh, xwt, adj, out, pdeg);
        finish_gtv<true><<<512, 256, 0, stream>>>(xw, nullptr, pdeg, bias, out);
    }
}

// Round 5
// 84.155 us; speedup vs baseline: 1.4113x; 1.0110x over previous
//
#include <hip/hip_runtime.h>
#include <hip/hip_fp16.h>

// Problem: B=2, N=1024, F_in=128, F_out=64
// out[b,i,f] = (1 - deg[b,i]) * xw[b,i,f] + sum_j w[b,i,j]*xw[b,j,f] + bias[f]
//   w[b,i,j] = adj[b,i,j] / max(L1(xw_i, xw_j), 1e-3), deg = row-sum of w
// Diagonal w_ii cancels identically in the output -> excluded from w and deg.
//
// R5: 64x64 (i,j) tiles, grid 512. Phase 1: packed-f16 L1 distances with 4x4
// register blocking + XOR-swizzled LDS (balanced banks). Phase 2: f16 MFMA.
// Partials stored f16 (half the reduce traffic). gemm k4-blocked.

#define JS 16
#define HSTR 72    // f16 row stride: 144 B (16B-aligned; swizzle balances banks)

typedef _Float16 half4_t __attribute__((ext_vector_type(4)));
typedef _Float16 half8_t __attribute__((ext_vector_type(8)));
typedef float    f32x4_t __attribute__((ext_vector_type(4)));

// ---------------- Kernel 1: xw = x @ W; emit f32, f16, f16-transposed ----
__global__ __launch_bounds__(256) void gemm_xw(const float* __restrict__ x,
                                               const float* __restrict__ w,
                                               float* __restrict__ xw,
                                               __half* __restrict__ xwh,
                                               __half* __restrict__ xwt) {
    __shared__ float ws_[128 * 64];   // 32 KB
    __shared__ float xs[8 * 132];
    __shared__ __half ts[8 * 64];     // transpose staging
    const int tid = threadIdx.x;
    const int r0  = blockIdx.x * 8;   // 256 blocks x 8 rows

#pragma unroll
    for (int e = tid; e < 2048; e += 256)
        ((float4*)ws_)[e] = ((const float4*)w)[e];
    {
        int row = tid >> 5, c = tid & 31;
        float4 v = *(const float4*)&x[(size_t)(r0 + row) * 128 + c * 4];
        *(float4*)&xs[row * 132 + c * 4] = v;
    }
    __syncthreads();

    const int rl = tid >> 5;   // 0..7
    const int fg = tid & 31;   // 2 features
    float2 acc = {0.f, 0.f};
#pragma unroll
    for (int k4 = 0; k4 < 32; ++k4) {
        float4 xv = *(const float4*)&xs[rl * 132 + k4 * 4];
        const float* xp = &xv.x;
#pragma unroll
        for (int m = 0; m < 4; ++m) {
            float2 wv = *(const float2*)&ws_[(k4 * 4 + m) * 64 + 2 * fg];
            acc.x += xp[m] * wv.x; acc.y += xp[m] * wv.y;
        }
    }
    size_t o = (size_t)(r0 + rl) * 64 + 2 * fg;
    *(float2*)&xw[o] = acc;
    __half2 h2 = __floats2half2_rn(acc.x, acc.y);
    *(__half2*)&xwh[o] = h2;
    *(__half2*)&ts[rl * 64 + 2 * fg] = h2;
    __syncthreads();

    if (tid < 64) {
        const int f = tid;
        const int b = r0 >> 10;
        const int n0 = r0 & 1023;
        __half hv[8];
#pragma unroll
        for (int r = 0; r < 8; ++r) hv[r] = ts[r * 64 + f];
        *(half8_t*)&xwt[((size_t)(b * 64 + f)) * 1024 + n0] = *(half8_t*)hv;
    }
}

// ---------------- Kernel 2: fused distances + MFMA aggregation ----------------
template <bool ATOMIC>
__global__ __launch_bounds__(256) void fused_gtv(const __half* __restrict__ xwh,
                                                 const __half* __restrict__ xwt,
                                                 const float* __restrict__ adj,
                                                 __half* __restrict__ part,
                                                 float* __restrict__ aout,
                                                 float* __restrict__ pdeg) {
    __shared__ __half xih[64 * HSTR];   // 9 KB [i][f], 16B-block swizzled
    __shared__ __half xjh[64 * HSTR];   // 9 KB [j][f], swizzled
    __shared__ __half xjt[64 * HSTR];   // 9 KB [f][j], linear (MFMA B)
    __shared__ __half wt [64 * HSTR];   // 9 KB [i][j], linear (MFMA A)

    const int tid = threadIdx.x;
    const int bx  = blockIdx.x;
    const int js  = bx & 15;
    const int it  = (bx >> 4) & 15;
    const int b   = bx >> 8;
    const int i0  = it * 64;
    const int j0  = js * 64;

    const __half* xhb = xwh + (size_t)b * 65536;
    const __half* xtb = xwt + (size_t)b * 65536;
    const float*  adjb = adj + (size_t)b * 1048576;

    const int ty = tid >> 4;   // 0..15 -> i rows 4ty..4ty+3
    const int tx = tid & 15;   // 0..15 -> j cols 4tx..4tx+3

    // prefetch adj 4x4 block (16 lanes x 16B = 256B contiguous per row)
    float4 av[4];
#pragma unroll
    for (int r = 0; r < 4; ++r)
        av[r] = *(const float4*)&adjb[(size_t)(i0 + 4 * ty + r) * 1024 + j0 + 4 * tx];

    // stage xih/xjh (swizzled) + xjt (linear): 512 x 16B each, 2 per thread
#pragma unroll
    for (int e = tid; e < 512; e += 256) {
        int row = e >> 3, cb = e & 7;
        int sc = ((cb ^ ((row >> 2) & 7)) << 3);
        float4 vi = *(const float4*)&xhb[(i0 + row) * 64 + cb * 8];
        *(float4*)&xih[row * HSTR + sc] = vi;
        float4 vj = *(const float4*)&xhb[(j0 + row) * 64 + cb * 8];
        *(float4*)&xjh[row * HSTR + sc] = vj;
        float4 vt = *(const float4*)&xtb[row * 1024 + j0 + cb * 8];  // row = f
        *(float4*)&xjt[row * HSTR + cb * 8] = vt;
    }
    __syncthreads();

    // ---- phase 1: 4x4 pairwise L1 distances, packed f16 ----
    __half2 acc[4][4];
#pragma unroll
    for (int r = 0; r < 4; ++r)
#pragma unroll
        for (int q = 0; q < 4; ++q) acc[r][q] = __floats2half2_rn(0.f, 0.f);

#pragma unroll
    for (int c = 0; c < 8; ++c) {
        const int ca = ((c ^ (ty & 7)) << 3);
        const int cb = ((c ^ (tx & 7)) << 3);
        float4 a[4], bb[4];
#pragma unroll
        for (int r = 0; r < 4; ++r)
            a[r] = *(const float4*)&xih[(4 * ty + r) * HSTR + ca];
#pragma unroll
        for (int q = 0; q < 4; ++q)
            bb[q] = *(const float4*)&xjh[(4 * tx + q) * HSTR + cb];
#pragma unroll
        for (int r = 0; r < 4; ++r) {
            const __half2* pa = (const __half2*)&a[r];
#pragma unroll
            for (int q = 0; q < 4; ++q) {
                const __half2* pb = (const __half2*)&bb[q];
#pragma unroll
                for (int m = 0; m < 4; ++m)
                    acc[r][q] = __hadd2(acc[r][q], __habs2(__hsub2(pa[m], pb[m])));
            }
        }
    }

    // w = adj/max(d,1e-3), diag excluded; write f16 wt[i][j]; deg via shfl
    float dsum[4];
#pragma unroll
    for (int r = 0; r < 4; ++r) {
        const int gi = i0 + 4 * ty + r;
        float wv[4];
        dsum[r] = 0.f;
#pragma unroll
        for (int q = 0; q < 4; ++q) {
            float d = __low2float(acc[r][q]) + __high2float(acc[r][q]);
            float v = (&av[r].x)[q] / fmaxf(d, 1e-3f);
            wv[q] = (gi == j0 + 4 * tx + q) ? 0.f : v;
            dsum[r] += wv[q];
        }
        float2 packed;
        ((__half2*)&packed)[0] = __floats2half2_rn(wv[0], wv[1]);
        ((__half2*)&packed)[1] = __floats2half2_rn(wv[2], wv[3]);
        *(float2*)&wt[(4 * ty + r) * HSTR + 4 * tx] = packed;
    }
#pragma unroll
    for (int r = 0; r < 4; ++r) {
#pragma unroll
        for (int m = 1; m < 16; m <<= 1)
            dsum[r] += __shfl_xor(dsum[r], m, 16);
    }
    if (tx == 0) {
#pragma unroll
        for (int r = 0; r < 4; ++r) {
            if (ATOMIC) atomicAdd(&pdeg[b * 1024 + i0 + 4 * ty + r], dsum[r]);
            else pdeg[(js * 2 + b) * 1024 + i0 + 4 * ty + r] = dsum[r];
        }
    }
    __syncthreads();

    // ---- phase 2: MFMA  P[64x64] = W[64xj64] x Xj[j64xf64] ----
    const int wv_  = tid >> 6;   // wave = m-tile
    const int lane = tid & 63;
    const int quad = lane >> 4;
    const int l15  = lane & 15;

    f32x4_t c[4] = {{0,0,0,0},{0,0,0,0},{0,0,0,0},{0,0,0,0}};
    half8_t a0 = *(half8_t*)&wt[(wv_ * 16 + l15) * HSTR + quad * 8];
    half8_t a1 = *(half8_t*)&wt[(wv_ * 16 + l15) * HSTR + 32 + quad * 8];
#pragma unroll
    for (int n = 0; n < 4; ++n) {
        half8_t b0 = *(half8_t*)&xjt[(n * 16 + l15) * HSTR + quad * 8];
        half8_t b1 = *(half8_t*)&xjt[(n * 16 + l15) * HSTR + 32 + quad * 8];
        c[n] = __builtin_amdgcn_mfma_f32_16x16x32_f16(a0, b0, c[n], 0, 0, 0);
        c[n] = __builtin_amdgcn_mfma_f32_16x16x32_f16(a1, b1, c[n], 0, 0, 0);
    }

    // epilogue: C row = wv_*16 + quad*4 + r, col = n*16 + l15
    if (ATOMIC) {
#pragma unroll
        for (int n = 0; n < 4; ++n)
#pragma unroll
            for (int r = 0; r < 4; ++r) {
                int row = wv_ * 16 + quad * 4 + r;
                atomicAdd(&aout[((size_t)b * 1024 + i0 + row) * 64 + n * 16 + l15], c[n][r]);
            }
    } else {
        const size_t slot = (size_t)(js * 2 + b) * 65536;
#pragma unroll
        for (int n = 0; n < 4; ++n)
#pragma unroll
            for (int r = 0; r < 4; ++r) {
                int row = wv_ * 16 + quad * 4 + r;
                part[slot + (i0 + row) * 64 + n * 16 + l15] = __float2half(c[n][r]);
            }
    }
}

// ---------------- Kernel 3: reduce partials + identity + bias ----------------
template <bool ATOMIC>
__global__ __launch_bounds__(256) void finish_gtv(const float* __restrict__ xw,
                                                  const __half* __restrict__ part,
                                                  const float* __restrict__ pdeg,
                                                  const float* __restrict__ bias,
                                                  float* __restrict__ out) {
    int idx = blockIdx.x * 256 + threadIdx.x;  // 0..131071
    int f = idx & 63;
    int r = idx >> 6;           // b*1024 + n
    int b = r >> 10;
    if (ATOMIC) {
        out[idx] = out[idx] + (1.f - pdeg[r]) * xw[idx] + bias[f];
    } else {
        int loc = idx & 65535;
        int n   = r & 1023;
        float s = 0.f, dgs = 0.f;
#pragma unroll
        for (int js = 0; js < JS; ++js) {
            s   += __half2float(part[(size_t)(js * 2 + b) * 65536 + loc]);
            dgs += pdeg[(js * 2 + b) * 1024 + n];
        }
        out[idx] = s + (1.f - dgs) * xw[idx] + bias[f];
    }
}

extern "C" void kernel_launch(void* const* d_in, const int* in_sizes, int n_in,
                              void* d_out, int out_size, void* d_ws, size_t ws_size,
                              hipStream_t stream) {
    const float* x    = (const float*)d_in[0];   // [2,1024,128]
    const float* adj  = (const float*)d_in[1];   // [2,1024,1024]
    const float* w    = (const float*)d_in[2];   // [128,64]
    const float* bias = (const float*)d_in[3];   // [64]
    float* out = (float*)d_out;                  // [2,1024,64]

    char* wsb = (char*)d_ws;
    float*  xw   = (float*)wsb;                      // 512 KB
    __half* xwh  = (__half*)(wsb + 512 * 1024);      // 256 KB  [b][n][f]
    __half* xwt  = (__half*)(wsb + 768 * 1024);      // 256 KB  [b][f][n]
    float*  pdeg = (float*)(wsb + 1024 * 1024);      // 128 KB (32 x 1024)
    __half* part = (__half*)(wsb + 1152 * 1024);     // 4 MB  (32 x 65536 f16)
    const size_t NEED = 1152 * 1024 + (size_t)32 * 65536 * 2;

    gemm_xw<<<256, 256, 0, stream>>>(x, w, xw, xwh, xwt);

    if (ws_size >= NEED) {
        fused_gtv<false><<<512, 256, 0, stream>>>(xwh, xwt, adj, part, nullptr, pdeg);
        finish_gtv<false><<<512, 256, 0, stream>>>(xw, part, pdeg, bias, out);
    } else {
        hipMemsetAsync(out, 0, 2 * 1024 * 64 * sizeof(float), stream);
        hipMemsetAsync(pdeg, 0, 2 * 1024 * sizeof(float), stream);
        fused_gtv<true><<<512, 256, 0, stream>>>(xwh, xwt, adj, nullptr, out, pdeg);
        finish_gtv<true><<<512, 256, 0, stream>>>(xw, nullptr, pdeg, bias, out);
    }
}